// Round 12
// baseline (227.074 us; speedup 1.0000x reference)
//
#include <hip/hip_runtime.h>
#include <math.h>
#include <stdint.h>

typedef _Float16 half8 __attribute__((ext_vector_type(8)));
typedef float floatx4 __attribute__((ext_vector_type(4)));

#define NTOK 16384
#define DIM  2048
#define NEXP 64
#define TPB  16                    // tokens per block
#define NBLK (NTOK / TPB)          // 1024 blocks -> 4 sequential rounds per CU
#define KSPL 8                     // K-split: one 256-k slice per wave
#define KW   (DIM / KSPL)          // 256 k per wave (1 KB per row)
#define KC   32                    // k per MFMA step
#define NCH  (KW / KC)             // 8 k-steps
#define WSW_H8 16384               // half8 slots per split
#define WSW_BYTES (2 * WSW_H8 * 16)

#define WAVE_B  16384              // wave A tile: 16 rows x 1 KB (FULL k-slice)
#define ARING_B (8 * WAVE_B)       // 128 KB; epilogue aliases 8 x 4 KB slabs
#define FIN_F   (TPB * 65)

// ---- prep: split W (fp32) into f16 hi + scaled-lo (2^11), B-fragment order:
// slot(sg,tg,lane) = (sg*4+tg)*64+lane holds W[tg*16+(lane&15)][sg*32+(lane>>4)*8 + 0..7]
__global__ void wprep_kernel(const float* __restrict__ W, _Float16* __restrict__ wsw) {
    const int id   = blockIdx.x * blockDim.x + threadIdx.x; // 0..16383
    const int lane = id & 63;
    const int tg   = (id >> 6) & 3;
    const int sg   = id >> 8;                               // 0..63
    const int e    = tg * 16 + (lane & 15);
    const int k    = sg * 32 + (lane >> 4) * 8;
    const float* src = W + (size_t)e * DIM + k;
    half8 h, l;
#pragma unroll
    for (int j = 0; j < 8; j++) {
        const float v  = src[j];
        const _Float16 hh = (_Float16)v;
        h[j] = hh;
        l[j] = (_Float16)((v - (float)hh) * 2048.0f);
    }
    const size_t slot = (size_t)(sg * 4 + tg) * 64 + lane;
    ((half8*)wsw)[slot]          = h;
    ((half8*)wsw)[WSW_H8 + slot] = l;
}

__device__ __forceinline__ void split_a(const float4& v0, const float4& v1,
                                        half8& hi, half8& lo) {
    const float av[8] = {v0.x, v0.y, v0.z, v0.w, v1.x, v1.y, v1.z, v1.w};
#pragma unroll
    for (int j = 0; j < 8; j++) {
        const _Float16 hh = (_Float16)av[j];
        hi[j] = hh;
        lo[j] = (_Float16)((av[j] - (float)hh) * 2048.0f);
    }
}

// async global->LDS DMA, 16 B/lane. LDS dest = WAVE-UNIFORM base (HW appends
// lane*16); GLOBAL source is per-lane (scatter allowed) -> swizzle the source.
__device__ __forceinline__ void dma16(const void* g, const char* l) {
    __builtin_amdgcn_global_load_lds(
        (const __attribute__((address_space(1))) unsigned int*)(uintptr_t)g,
        (__attribute__((address_space(3))) unsigned int*)(uintptr_t)l,
        16, 0, 0);
}

template <int N>
__device__ __forceinline__ void wait_vm() {
    asm volatile("s_waitcnt vmcnt(%0)" :: "n"(N) : "memory");
}

__device__ __forceinline__ void fence_order() {
    asm volatile("" ::: "memory");   // seal VMEM issue order (counted-vmcnt rule)
}

// CONTIGUITY + DEEP-IN-FLIGHT probe (R11 + the missing order fence).
// All prior rounds read x as 128-256 B row-slivers at 8 KB stride with <=8 KB
// per wave in flight (Little's law: 8 KB / ~1us HBM RTT = 8 GB/s/CU = measured).
// Here:
//  - each dma op stages ONE row's full 1 KB k-slice (64 lanes x 16 B, sequential)
//  - the wave's ENTIRE A tile (16 rows = 16 ops) is issued in one burst
//    -> 128 KB in flight per CU, ONE counted wait, then compute runs from LDS.
// Issue order SEALED by fences: [A x16][fence][B(0) x8][wait vmcnt(8)] — R11
// omitted the fence, the compiler hoisted B loads above A dmas, vmcnt(8)
// under-waited the A tail -> garbage logits (absmax 63). Same lesson as R4:
// a counted vmcnt is only valid with fence-sealed issue order.
// XOR piece-swizzle on the GLOBAL source (lane^(r&7)); LDS stays linear
// (global_load_lds rule); un-XOR on the ds_read -> <=2-way bank aliasing (free).
template <bool USE_WS>
__global__ __launch_bounds__(512, 2)
void gating_kernel(const float* __restrict__ x, const float* __restrict__ W,
                   const _Float16* __restrict__ wsw, const float* __restrict__ bias,
                   float* __restrict__ out)
{
    __shared__ char  aring[ARING_B];   // staging; epilogue: 8 x 4 KB slabs
    __shared__ float fin[FIN_F];
    __shared__ float bsh[NEXP];

    const int tid  = threadIdx.x;
    const int lane = tid & 63;
    const int ks   = tid >> 6;          // 0..7: K-slice (wave id)
    const int col  = lane & 15;
    const int quad = lane >> 4;
    const int tok0 = blockIdx.x * TPB;

    if (tid < NEXP) bsh[tid] = bias[tid];

    char* const wbase = aring + ks * WAVE_B;

    // ---- stage the whole wave tile: op r = row tok0+r, 1 KB contiguous slice.
    // lane l fetches global piece l^(r&7) -> LDS piece l holds global piece l^(r&7).
    {
        const float* rowp = x + (size_t)tok0 * DIM + ks * KW;
#pragma unroll
        for (int r = 0; r < TPB; r++)
            dma16(rowp + (size_t)r * DIM + ((lane ^ (r & 7)) << 2),
                  wbase + r * 1024);
    }
    fence_order();   // all 16 A dmas issued BEFORE anything below (vmcnt count)

    floatx4 accm[4], accl[4];
#pragma unroll
    for (int t = 0; t < 4; t++) { accm[t] = (floatx4){0,0,0,0}; accl[t] = (floatx4){0,0,0,0}; }

    // ---- B(0) prefetch (8 VMEM ops in both variants), then the single A wait:
    // outstanding = [bias?, A x16 (older)] + [B0 x8 (newer)]; vmcnt(8) -> A landed.
    half8  bh[2][4], bl[2][4];
    float4 bf0[2][4], bf1[2][4];
    if constexpr (USE_WS) {
#pragma unroll
        for (int t = 0; t < 4; t++) {
            const size_t o = (size_t)((ks * NCH + 0) * 4 + t) * 64 + lane;
            bh[0][t] = ((const half8*)wsw)[o];
            bl[0][t] = ((const half8*)wsw)[WSW_H8 + o];
        }
    } else {
#pragma unroll
        for (int t = 0; t < 4; t++) {
            const float* wr = W + (size_t)(t * 16 + col) * DIM + (ks * NCH) * 32 + quad * 8;
            bf0[0][t] = *(const float4*)wr;
            bf1[0][t] = *(const float4*)(wr + 4);
        }
    }
    wait_vm<8>();

    // ---- k-loop: 8 steps, all data in LDS / registers. No barriers, no manual
    // waits (compiler tracks B-register deps and ds_read deps itself).
#pragma unroll
    for (int c = 0; c < NCH; ++c) {
        const int cur = c & 1, nxt = cur ^ 1;
        if (c + 1 < NCH) {
            if constexpr (USE_WS) {
#pragma unroll
                for (int t = 0; t < 4; t++) {
                    const size_t o = (size_t)((ks * NCH + c + 1) * 4 + t) * 64 + lane;
                    bh[nxt][t] = ((const half8*)wsw)[o];
                    bl[nxt][t] = ((const half8*)wsw)[WSW_H8 + o];
                }
            } else {
#pragma unroll
                for (int t = 0; t < 4; t++) {
                    const float* wr = W + (size_t)(t * 16 + col) * DIM + (ks * NCH + c + 1) * 32 + quad * 8;
                    bf0[nxt][t] = *(const float4*)wr;
                    bf1[nxt][t] = *(const float4*)(wr + 4);
                }
            }
        }
        // A frag: token row = col; global pieces c*8+quad*2, +1; un-XOR by col&7.
        const int pz0 = (c * 8 + quad * 2 + 0) ^ (col & 7);
        const int pz1 = (c * 8 + quad * 2 + 1) ^ (col & 7);
        const float4 v0 = *(const float4*)(wbase + col * 1024 + pz0 * 16);
        const float4 v1 = *(const float4*)(wbase + col * 1024 + pz1 * 16);
        half8 ah, al;
        split_a(v0, v1, ah, al);
#pragma unroll
        for (int t = 0; t < 4; t++) {
            half8 hb, lb;
            if constexpr (USE_WS) { hb = bh[cur][t]; lb = bl[cur][t]; }
            else                  { split_a(bf0[cur][t], bf1[cur][t], hb, lb); }
            accm[t] = __builtin_amdgcn_mfma_f32_16x16x32_f16(ah, hb, accm[t], 0, 0, 0);
            accl[t] = __builtin_amdgcn_mfma_f32_16x16x32_f16(ah, lb, accl[t], 0, 0, 0);
            accl[t] = __builtin_amdgcn_mfma_f32_16x16x32_f16(al, hb, accl[t], 0, 0, 0);
        }
    }

    __syncthreads();      // all waves done reading their tiles; alias slabs
    {   // wave ks writes its 16x64 K-partial into slab ks (4 KB)
        float* slab = (float*)(aring + ks * 4096);
        const float inv = 1.0f / 2048.0f;
#pragma unroll
        for (int t = 0; t < 4; t++)
#pragma unroll
            for (int r = 0; r < 4; r++)   // C/D: row=quad*4+r (token), col=lane&15 [m89]
                slab[(quad * 4 + r) * 64 + t * 16 + col] =
                    accm[t][r] + accl[t][r] * inv;
    }
    __syncthreads();
    {   // 512 threads: sum 8 slabs + bias -> fin[16][65] (2 experts per thread)
        const int tk = tid >> 5;          // 0..15
        const int e0 = (tid & 31) * 2;    // 0..62
        float s0 = 0.f, s1 = 0.f;
#pragma unroll
        for (int p = 0; p < KSPL; p++) {
            const float* sb = (const float*)(aring + p * 4096) + tk * 64 + e0;
            s0 += sb[0];
            s1 += sb[1];
        }
        fin[tk * 65 + e0]     = s0 + bsh[e0];
        fin[tk * 65 + e0 + 1] = s1 + bsh[e0 + 1];
    }
    __syncthreads();

    if (tid < TPB) {
        const int tk = tid;
        float v0 = -INFINITY, v1 = -INFINITY;
        int   i0 = 0, i1 = 0;
        for (int e = 0; e < NEXP; e++) {
            const float v = fin[tk * 65 + e];
            if (v > v0)      { v1 = v0; i1 = i0; v0 = v; i0 = e; }
            else if (v > v1) { v1 = v; i1 = e; }
        }
        const float e1 = expf(v1 - v0);   // v1 <= v0: stable
        const float sden = 1.f + e1;
        const int   g  = tok0 + tk;
        out[2 * g + 0] = 1.f / sden;
        out[2 * g + 1] = e1 / sden;
        out[2 * NTOK + 2 * g + 0] = (float)i0;
        out[2 * NTOK + 2 * g + 1] = (float)i1;
    }
}

extern "C" void kernel_launch(void* const* d_in, const int* in_sizes, int n_in,
                              void* d_out, int out_size, void* d_ws, size_t ws_size,
                              hipStream_t stream) {
    const float* x    = (const float*)d_in[0];
    const float* W    = (const float*)d_in[1];
    const float* bias = (const float*)d_in[2];
    float*       out  = (float*)d_out;
    _Float16*    wsw  = (_Float16*)d_ws;

    if (ws_size >= (size_t)WSW_BYTES) {
        hipLaunchKernelGGL(wprep_kernel, dim3(64), dim3(256), 0, stream, W, wsw);
        hipLaunchKernelGGL((gating_kernel<true>), dim3(NBLK), dim3(512), 0, stream,
                           x, W, wsw, bias, out);
    } else {
        hipLaunchKernelGGL((gating_kernel<false>), dim3(NBLK), dim3(512), 0, stream,
                           x, W, nullptr, bias, out);
    }
}

// Round 13
// 213.470 us; speedup vs baseline: 1.0637x; 1.0637x over previous
//
#include <hip/hip_runtime.h>
#include <math.h>
#include <stdint.h>

typedef _Float16 half8 __attribute__((ext_vector_type(8)));
typedef float floatx4 __attribute__((ext_vector_type(4)));

#define NTOK 16384
#define DIM  2048
#define NEXP 64
#define TPB  64                    // tokens per block (byte-minimal: W once/64 tok)
#define NBLK (NTOK / TPB)          // 256 blocks = 1 per CU
#define SCK  256                   // k per super-chunk
#define NSC  (DIM / SCK)           // 8 super-chunks
#define WSW_H8 16384               // half8 slots per split
#define WSW_BYTES (2 * WSW_H8 * 16)

#define SLOT_B 65536               // A slot: 64 rows x 1 KB (256 k each)
#define RING_B (2 * SLOT_B)        // 128 KB ring; epilogue aliases 8 x 16 KB slabs
#define FIN_F  (TPB * 65)

// ---- prep: split W (fp32) into f16 hi + scaled-lo (2^11), B-fragment order:
// slot(sg,tg,lane) = (sg*4+tg)*64+lane holds W[tg*16+(lane&15)][sg*32+(lane>>4)*8 + 0..7]
__global__ void wprep_kernel(const float* __restrict__ W, _Float16* __restrict__ wsw) {
    const int id   = blockIdx.x * blockDim.x + threadIdx.x; // 0..16383
    const int lane = id & 63;
    const int tg   = (id >> 6) & 3;
    const int sg   = id >> 8;                               // 0..63
    const int e    = tg * 16 + (lane & 15);
    const int k    = sg * 32 + (lane >> 4) * 8;
    const float* src = W + (size_t)e * DIM + k;
    half8 h, l;
#pragma unroll
    for (int j = 0; j < 8; j++) {
        const float v  = src[j];
        const _Float16 hh = (_Float16)v;
        h[j] = hh;
        l[j] = (_Float16)((v - (float)hh) * 2048.0f);
    }
    const size_t slot = (size_t)(sg * 4 + tg) * 64 + lane;
    ((half8*)wsw)[slot]          = h;
    ((half8*)wsw)[WSW_H8 + slot] = l;
}

__device__ __forceinline__ void split_a(const float4& v0, const float4& v1,
                                        half8& hi, half8& lo) {
    const float av[8] = {v0.x, v0.y, v0.z, v0.w, v1.x, v1.y, v1.z, v1.w};
#pragma unroll
    for (int j = 0; j < 8; j++) {
        const _Float16 hh = (_Float16)av[j];
        hi[j] = hh;
        lo[j] = (_Float16)((av[j] - (float)hh) * 2048.0f);
    }
}

// async global->LDS DMA, 16 B/lane. LDS dest = WAVE-UNIFORM base (HW appends
// lane*16); GLOBAL source is per-lane -> swizzle the source, LDS stays linear.
__device__ __forceinline__ void dma16(const void* g, const char* l) {
    __builtin_amdgcn_global_load_lds(
        (const __attribute__((address_space(1))) unsigned int*)(uintptr_t)g,
        (__attribute__((address_space(3))) unsigned int*)(uintptr_t)l,
        16, 0, 0);
}

template <int N>
__device__ __forceinline__ void wait_vm() {
    asm volatile("s_waitcnt vmcnt(%0)" :: "n"(N) : "memory");
}

__device__ __forceinline__ void fence_order() {
    asm volatile("" ::: "memory");   // seal VMEM issue order (counted-vmcnt rule)
}

// Byte-minimal + contiguous + deep-in-flight, simultaneously (first time):
//  - bytes: A once (512 KB/CU) + W once per 64-tok block (512 KB/CU) = 1 MB/CU
//  - contiguity: EVERY VMEM op (A dma & B load) is a 1-KB sequential burst
//  - in flight: 64 KB A per super-chunk + 8 KB B per wave; one counted wait per SC
// Block-shared A ring-2 (64 KB slots); 8 waves K-split WITHIN each super-chunk
// (wave w owns k-step w of 8) so W is read exactly once per block, register-B.
// Sync per SC (R6-proven ordering; races excluded per R4 lesson):
//   [B(sc) x8][fence][wait vmcnt(8): A(sc) landed, B still in flight]
//   [s_barrier: slot sc&1 staged block-wide; compute(sc-1) done everywhere]
//   [A(sc+1) x8 into slot (sc+1)&1 — safe ONLY here][fence][compute(sc)]
template <bool USE_WS>
__global__ __launch_bounds__(512, 2)
void gating_kernel(const float* __restrict__ x, const float* __restrict__ W,
                   const _Float16* __restrict__ wsw, const float* __restrict__ bias,
                   float* __restrict__ out)
{
    __shared__ char  aring[RING_B];    // 128 KB; epilogue: 8 x 16 KB slabs
    __shared__ float fin[FIN_F];       // 16.6 KB
    __shared__ float bsh[NEXP];

    const int tid  = threadIdx.x;
    const int lane = tid & 63;
    const int w    = tid >> 6;          // 0..7: wave id = k-step within each SC
    const int col  = lane & 15;
    const int quad = lane >> 4;
    const int tok0 = blockIdx.x * TPB;

    if (tid < NEXP) bsh[tid] = bias[tid];

    // ---- A staging: wave w stages rows w*8..w*8+7; one op = one row's 1-KB
    // slice (64 lanes x 16 B sequential). XOR piece-swizzle on the GLOBAL side:
    // LDS piece l holds global piece l^(row&7); un-XOR on the ds_read.
    // prologue: SC 0 -> slot 0
#pragma unroll
    for (int i = 0; i < 8; i++) {
        const int rw = w * 8 + i;
        dma16(x + (size_t)(tok0 + rw) * DIM + ((lane ^ (rw & 7)) << 2),
              aring + rw * 1024);
    }
    fence_order();

    floatx4 accm[4][4], accl[4][4];
#pragma unroll
    for (int m = 0; m < 4; m++)
#pragma unroll
        for (int t = 0; t < 4; t++) { accm[m][t] = (floatx4){0,0,0,0}; accl[m][t] = (floatx4){0,0,0,0}; }

#pragma unroll
    for (int sc = 0; sc < NSC; ++sc) {
        // ---- B(sc): wave's k-step sg = sc*8+w; 8 x 1-KB loads (4 tg hi + 4 lo)
        const int sg = sc * 8 + w;
        half8  bh[4], bl[4];
        float4 bf0[4], bf1[4];
        if constexpr (USE_WS) {
#pragma unroll
            for (int t = 0; t < 4; t++) {
                bh[t] = ((const half8*)wsw)[(size_t)(sg * 4 + t) * 64 + lane];
                bl[t] = ((const half8*)wsw)[WSW_H8 + (size_t)(sg * 4 + t) * 64 + lane];
            }
        } else {
#pragma unroll
            for (int t = 0; t < 4; t++) {
                const float* wr = W + (size_t)(t * 16 + col) * DIM + sg * 32 + quad * 8;
                bf0[t] = *(const float4*)wr;
                bf1[t] = *(const float4*)(wr + 4);
            }
        }
        fence_order();
        // outstanding: [A(sc) x8 older][B(sc) x8 newer] (+older bias on wave 0)
        wait_vm<8>();                       // A(sc) landed; B may still fly
        __builtin_amdgcn_s_barrier();       // slot sc&1 staged block-wide
        fence_order();
        if (sc + 1 < NSC) {                 // safe only after the barrier (R4)
#pragma unroll
            for (int i = 0; i < 8; i++) {
                const int rw = w * 8 + i;
                dma16(x + (size_t)(tok0 + rw) * DIM + (sc + 1) * SCK + ((lane ^ (rw & 7)) << 2),
                      aring + ((sc + 1) & 1) * SLOT_B + rw * 1024);
            }
            fence_order();
        }

        // ---- compute(sc): A frags from slot sc&1, k-pieces w*8+quad*2(+1)
        const char* Ab = aring + (sc & 1) * SLOT_B;
#pragma unroll
        for (int m = 0; m < 4; m++) {
            const int row = m * 16 + col;
            const int pz0 = (w * 8 + quad * 2 + 0) ^ (col & 7);
            const int pz1 = (w * 8 + quad * 2 + 1) ^ (col & 7);
            const float4 v0 = *(const float4*)(Ab + row * 1024 + pz0 * 16);
            const float4 v1 = *(const float4*)(Ab + row * 1024 + pz1 * 16);
            half8 ah, al;
            split_a(v0, v1, ah, al);
#pragma unroll
            for (int t = 0; t < 4; t++) {
                half8 hb, lb;
                if constexpr (USE_WS) { hb = bh[t]; lb = bl[t]; }
                else                  { split_a(bf0[t], bf1[t], hb, lb); }
                accm[m][t] = __builtin_amdgcn_mfma_f32_16x16x32_f16(ah, hb, accm[m][t], 0, 0, 0);
                accl[m][t] = __builtin_amdgcn_mfma_f32_16x16x32_f16(ah, lb, accl[m][t], 0, 0, 0);
                accl[m][t] = __builtin_amdgcn_mfma_f32_16x16x32_f16(al, hb, accl[m][t], 0, 0, 0);
            }
        }
    }

    __syncthreads();      // all waves done with the ring; alias 8 slabs
    {   // wave w writes its 64x64 K-partial into slab w (16 KB)
        float* slab = (float*)(aring + w * 16384);
        const float inv = 1.0f / 2048.0f;
#pragma unroll
        for (int m = 0; m < 4; m++)
#pragma unroll
            for (int t = 0; t < 4; t++)
#pragma unroll
                for (int r = 0; r < 4; r++)   // C/D: row=quad*4+r, col=lane&15 [m89]
                    slab[(m * 16 + quad * 4 + r) * 64 + t * 16 + col] =
                        accm[m][t][r] + accl[m][t][r] * inv;
    }
    __syncthreads();
    {   // 512 threads: sum 8 slabs + bias -> fin[64][65]
        const int tk = tid >> 3;          // 0..63
        const int e0 = (tid & 7) * 8;     // 0..56
        floatx4 s0 = {0,0,0,0}, s1 = {0,0,0,0};
#pragma unroll
        for (int p = 0; p < 8; p++) {
            const float* sb = (const float*)(aring + p * 16384) + tk * 64 + e0;
            s0 += *(const floatx4*)sb;
            s1 += *(const floatx4*)(sb + 4);
        }
#pragma unroll
        for (int j = 0; j < 4; j++) {
            fin[tk * 65 + e0 + j]     = s0[j] + bsh[e0 + j];
            fin[tk * 65 + e0 + 4 + j] = s1[j] + bsh[e0 + 4 + j];
        }
    }
    __syncthreads();

    if (tid < TPB) {
        const int tk = tid;
        float v0 = -INFINITY, v1 = -INFINITY;
        int   i0 = 0, i1 = 0;
        for (int e = 0; e < NEXP; e++) {
            const float v = fin[tk * 65 + e];
            if (v > v0)      { v1 = v0; i1 = i0; v0 = v; i0 = e; }
            else if (v > v1) { v1 = v; i1 = e; }
        }
        const float e1 = expf(v1 - v0);   // v1 <= v0: stable
        const float sden = 1.f + e1;
        const int   g  = tok0 + tk;
        out[2 * g + 0] = 1.f / sden;
        out[2 * g + 1] = e1 / sden;
        out[2 * NTOK + 2 * g + 0] = (float)i0;
        out[2 * NTOK + 2 * g + 1] = (float)i1;
    }
}

extern "C" void kernel_launch(void* const* d_in, const int* in_sizes, int n_in,
                              void* d_out, int out_size, void* d_ws, size_t ws_size,
                              hipStream_t stream) {
    const float* x    = (const float*)d_in[0];
    const float* W    = (const float*)d_in[1];
    const float* bias = (const float*)d_in[2];
    float*       out  = (float*)d_out;
    _Float16*    wsw  = (_Float16*)d_ws;

    if (ws_size >= (size_t)WSW_BYTES) {
        hipLaunchKernelGGL(wprep_kernel, dim3(64), dim3(256), 0, stream, W, wsw);
        hipLaunchKernelGGL((gating_kernel<true>), dim3(NBLK), dim3(512), 0, stream,
                           x, W, wsw, bias, out);
    } else {
        hipLaunchKernelGGL((gating_kernel<false>), dim3(NBLK), dim3(512), 0, stream,
                           x, W, nullptr, bias, out);
    }
}

// Round 14
// 203.812 us; speedup vs baseline: 1.1141x; 1.0474x over previous
//
#include <hip/hip_runtime.h>
#include <math.h>
#include <stdint.h>

typedef _Float16 half8 __attribute__((ext_vector_type(8)));
typedef float floatx4 __attribute__((ext_vector_type(4)));

#define NTOK 16384
#define DIM  2048
#define NEXP 64
#define MB   64                    // tokens per block
#define NBLK (NTOK / MB)           // 256 blocks = 1 per CU
#define KSPL 8                     // K-split: one slice per wave
#define KW   (DIM / KSPL)          // 256 k per wave
#define NCH  (KW / 32)             // 8 chunks (1 MFMA k-step each)
#define WSW_H8 16384               // half8 slots per split
#define WSW_BYTES (2 * WSW_H8 * 16)

#define SLOT_B  8192               // A slot: 64 rows x 128 B (one 32-k chunk)
#define WAVE_B  (2 * SLOT_B)       // ring-2, wave-private
#define ARING_B (8 * WAVE_B)       // 128 KB; aliased by 8 reduction slabs (8 x 16 KB)
#define FIN_F   (64 * 65)          // final logits, stride-65 (conflict-free scan)

// ---- prep: split W (fp32) into f16 hi + scaled-lo (2^11), B-fragment order:
// slot(sg,tg,lane) = (sg*4+tg)*64+lane holds W[tg*16+(lane&15)][sg*32+(lane>>4)*8 + 0..7]
__global__ void wprep_kernel(const float* __restrict__ W, _Float16* __restrict__ wsw) {
    const int id   = blockIdx.x * blockDim.x + threadIdx.x; // 0..16383
    const int lane = id & 63;
    const int tg   = (id >> 6) & 3;
    const int sg   = id >> 8;                               // 0..63
    const int e    = tg * 16 + (lane & 15);
    const int k    = sg * 32 + (lane >> 4) * 8;
    const float* src = W + (size_t)e * DIM + k;
    half8 h, l;
#pragma unroll
    for (int j = 0; j < 8; j++) {
        const float v  = src[j];
        const _Float16 hh = (_Float16)v;
        h[j] = hh;
        l[j] = (_Float16)((v - (float)hh) * 2048.0f);
    }
    const size_t slot = (size_t)(sg * 4 + tg) * 64 + lane;
    ((half8*)wsw)[slot]          = h;
    ((half8*)wsw)[WSW_H8 + slot] = l;
}

__device__ __forceinline__ void split_a(const float4& v0, const float4& v1,
                                        half8& hi, half8& lo) {
    const float av[8] = {v0.x, v0.y, v0.z, v0.w, v1.x, v1.y, v1.z, v1.w};
#pragma unroll
    for (int j = 0; j < 8; j++) {
        const _Float16 hh = (_Float16)av[j];
        hi[j] = hh;
        lo[j] = (_Float16)((av[j] - (float)hh) * 2048.0f);
    }
}

// async global->LDS DMA, 16 B/lane. LDS dest = WAVE-UNIFORM base (HW appends lane*16).
__device__ __forceinline__ void dma16(const void* g, const char* l) {
    __builtin_amdgcn_global_load_lds(
        (const __attribute__((address_space(1))) unsigned int*)(uintptr_t)g,
        (__attribute__((address_space(3))) unsigned int*)(uintptr_t)l,
        16, 0, 0);
}

template <int N>
__device__ __forceinline__ void wait_vm() {
    asm volatile("s_waitcnt vmcnt(%0)" :: "n"(N) : "memory");
}

// 8-way K-split, BARRIER-FREE k-loop (empirical optimum of the session; 203.5 us
// headline, gating ~63 us). Wave ks owns 64 tok x 64 exp x k-slice
// [ks*256, ks*256+256). A staged in wave-PRIVATE LDS ring-2 via global_load_lds;
// B fragments loaded straight from wsw (L2-hot, read once per block - the k-split
// IS the B-dedup, no cross-wave sharing so no barriers).
// Per iter c (fences seal order):  [B(c) 8 loads][A-dma(c+1) 8 ops]
//   [wait vmcnt(16): newer-than-A(c) = B(c)8 + A(c+1)8 -> A(c) landed]
//   [ds_read frags slot c&1, 48 MFMA]   (compiler emits its own waits for B regs)
// Session conclusion (13 rounds): per-CU VMEM ingest rate is set by op contiguity
// x CU-never-quiet; under the 160 KB LDS budget, {1-KB A-ops, B-read-once,
// barrier-free} are mutually exclusive - this config (sliver-A, minimal bytes,
// barrier-free) is the measured optimum of the feasible set.
template <bool USE_WS>
__global__ __launch_bounds__(512, 2)
void gating_kernel(const float* __restrict__ x, const float* __restrict__ W,
                   const _Float16* __restrict__ wsw, const float* __restrict__ bias,
                   float* __restrict__ out)
{
    __shared__ char  aring[ARING_B];   // 128 KB: k-loop A ring; epilogue: 8 slabs
    __shared__ float fin[FIN_F];       // 16.6 KB
    __shared__ float bsh[NEXP];

    const int tid  = threadIdx.x;
    const int lane = tid & 63;
    const int ks   = tid >> 6;          // 0..7: K-slice (wave id)
    const int col  = lane & 15;
    const int quad = lane >> 4;
    const int tok0 = blockIdx.x * MB;

    if (tid < NEXP) bsh[tid] = bias[tid];

    // A dma: op i covers rows 8i..8i+7 (128 B per row-chunk). XOR piece swizzle:
    // lane: row-in-op = lane>>3, LDS piece pz = lane&7 holds global piece pz^row.
    const int arow = lane >> 3;
    const int agp  = (lane & 7) ^ arow;       // (8i+arow)&7 == arow for all i
    const float* gA = x + (size_t)(tok0 + arow) * DIM + ks * KW + agp * 4;
    char* const wbase = aring + ks * WAVE_B;  // wave-private ring

    floatx4 accm[4][4], accl[4][4];
#pragma unroll
    for (int m = 0; m < 4; m++)
#pragma unroll
        for (int t = 0; t < 4; t++) { accm[m][t] = (floatx4){0,0,0,0}; accl[m][t] = (floatx4){0,0,0,0}; }

    // prologue: chunk 0 -> slot 0
#pragma unroll
    for (int i = 0; i < 8; i++)
        dma16(gA + (size_t)i * 8 * DIM, wbase + i * 1024);

#pragma unroll
    for (int c = 0; c < NCH; ++c) {
        const int sg = ks * NCH + c;          // global k-step 0..63
        half8  bh[4], bl[4];
        float4 bf0[4], bf1[4];
        if constexpr (USE_WS) {
#pragma unroll
            for (int t = 0; t < 4; t++) {
                bh[t] = ((const half8*)wsw)[(size_t)(sg * 4 + t) * 64 + lane];
                bl[t] = ((const half8*)wsw)[WSW_H8 + (size_t)(sg * 4 + t) * 64 + lane];
            }
        } else {
#pragma unroll
            for (int t = 0; t < 4; t++) {
                const float* wr = W + (size_t)(t * 16 + col) * DIM + sg * 32 + quad * 8;
                bf0[t] = *(const float4*)wr;
                bf1[t] = *(const float4*)(wr + 4);
            }
        }
        asm volatile("" ::: "memory");
        if (c + 1 < NCH) {
#pragma unroll
            for (int i = 0; i < 8; i++)
                dma16(gA + (size_t)i * 8 * DIM + (c + 1) * 32,
                      wbase + ((c + 1) & 1) * SLOT_B + i * 1024);
        }
        asm volatile("" ::: "memory");
        if (c + 1 < NCH) wait_vm<16>();   // newer = B(c)8 + A(c+1)8; A(c) landed
        else             wait_vm<8>();    // newer = B(c)8 only
        asm volatile("" ::: "memory");

        const char* Ab = wbase + (c & 1) * SLOT_B;
#pragma unroll
        for (int m = 0; m < 4; m++) {
            const int row = m * 16 + col;
            const float4 v0 = *(const float4*)(Ab + row * 128 + (((2 * quad + 0) ^ (col & 7))) * 16);
            const float4 v1 = *(const float4*)(Ab + row * 128 + (((2 * quad + 1) ^ (col & 7))) * 16);
            half8 ah, al;
            split_a(v0, v1, ah, al);
#pragma unroll
            for (int t = 0; t < 4; t++) {
                half8 hb, lb;
                if constexpr (USE_WS) { hb = bh[t]; lb = bl[t]; }
                else                  { split_a(bf0[t], bf1[t], hb, lb); }
                accm[m][t] = __builtin_amdgcn_mfma_f32_16x16x32_f16(ah, hb, accm[m][t], 0, 0, 0);
                accl[m][t] = __builtin_amdgcn_mfma_f32_16x16x32_f16(ah, lb, accl[m][t], 0, 0, 0);
                accl[m][t] = __builtin_amdgcn_mfma_f32_16x16x32_f16(al, hb, accl[m][t], 0, 0, 0);
            }
        }
    }

    __syncthreads();      // single sync: all waves done with A-ring; alias slabs
    {   // wave ks writes its 64x64 K-partial into slab ks
        float* slab = (float*)(aring + ks * 16384);
        const float inv = 1.0f / 2048.0f;
#pragma unroll
        for (int m = 0; m < 4; m++)
#pragma unroll
            for (int t = 0; t < 4; t++)
#pragma unroll
                for (int r = 0; r < 4; r++)   // C/D: row=quad*4+r, col=lane&15 [m89]
                    slab[(m * 16 + quad * 4 + r) * 64 + t * 16 + col] =
                        accm[m][t][r] + accl[m][t][r] * inv;
    }
    __syncthreads();
    {   // 512 threads: sum 8 slabs + bias -> fin[64][65]
        const int tk = tid >> 3;
        const int e0 = (tid & 7) * 8;
        floatx4 s0 = {0,0,0,0}, s1 = {0,0,0,0};
#pragma unroll
        for (int p = 0; p < KSPL; p++) {
            const float* sb = (const float*)(aring + p * 16384) + tk * 64 + e0;
            s0 += *(const floatx4*)sb;
            s1 += *(const floatx4*)(sb + 4);
        }
#pragma unroll
        for (int j = 0; j < 4; j++) {
            fin[tk * 65 + e0 + j]     = s0[j] + bsh[e0 + j];
            fin[tk * 65 + e0 + 4 + j] = s1[j] + bsh[e0 + 4 + j];
        }
    }
    __syncthreads();

    if (tid < MB) {
        const int tk = tid;
        float v0 = -INFINITY, v1 = -INFINITY;
        int   i0 = 0, i1 = 0;
        for (int e = 0; e < NEXP; e++) {
            const float v = fin[tk * 65 + e];
            if (v > v0)      { v1 = v0; i1 = i0; v0 = v; i0 = e; }
            else if (v > v1) { v1 = v; i1 = e; }
        }
        const float e1 = expf(v1 - v0);   // v1 <= v0: stable
        const float sden = 1.f + e1;
        const int   g  = tok0 + tk;
        out[2 * g + 0] = 1.f / sden;
        out[2 * g + 1] = e1 / sden;
        out[2 * NTOK + 2 * g + 0] = (float)i0;
        out[2 * NTOK + 2 * g + 1] = (float)i1;
    }
}

extern "C" void kernel_launch(void* const* d_in, const int* in_sizes, int n_in,
                              void* d_out, int out_size, void* d_ws, size_t ws_size,
                              hipStream_t stream) {
    const float* x    = (const float*)d_in[0];
    const float* W    = (const float*)d_in[1];
    const float* bias = (const float*)d_in[2];
    float*       out  = (float*)d_out;
    _Float16*    wsw  = (_Float16*)d_ws;

    if (ws_size >= (size_t)WSW_BYTES) {
        hipLaunchKernelGGL(wprep_kernel, dim3(64), dim3(256), 0, stream, W, wsw);
        hipLaunchKernelGGL((gating_kernel<true>), dim3(NBLK), dim3(512), 0, stream,
                           x, W, wsw, bias, out);
    } else {
        hipLaunchKernelGGL((gating_kernel<false>), dim3(NBLK), dim3(512), 0, stream,
                           x, W, nullptr, bias, out);
    }
}